// Round 4
// baseline (308.881 us; speedup 1.0000x reference)
//
#include <hip/hip_runtime.h>
#include <hip/hip_bf16.h>
#include <stdint.h>

#define N_NODES 50000
#define N_EDGES 800000
#define H_DIM 128
#define N_REL 40
#define N_BASES 4
#define A_COLS 640           // [hbf(128) | S(512)] unified per-node row
#define N_ROWS_PAD 50048     // 782 blocks * 64 rows

typedef __attribute__((ext_vector_type(8))) short bf16x8;
typedef __attribute__((ext_vector_type(4))) float f32x4;

// round-to-nearest-even f32 -> bf16 bits
__device__ __forceinline__ unsigned short f2bf(float f) {
    unsigned int u = __float_as_uint(f);
    unsigned int r = u + 0x7fffu + ((u >> 16) & 1u);
    return (unsigned short)(r >> 16);
}

// ---------------------------------------------------------------------------
// K0 "prep": blocks 0..3124  -> cast h into A[:,0:128] (bf16) + dst histogram
//            blocks 3125..3129 -> transpose loop_w/basis_w into wt2 (bf16)
// wt2[j][kg] = Wstack[kg][j], Wstack = [loop_w ; basis_w[0..3]]  (640 x 128)
__global__ __launch_bounds__(256) void prep_kernel(
        const float* __restrict__ h, const int* __restrict__ dst,
        const float* __restrict__ basis_w, const float* __restrict__ loop_w,
        unsigned short* __restrict__ A, int* __restrict__ cnt,
        unsigned short* __restrict__ wt2) {
    int bid = blockIdx.x;
    if (bid < 3125) {
        int t = bid * 256 + threadIdx.x;        // [0, 800000)
        // cast: 8 elems of h per thread
        int row = t >> 4;
        int cb = (t & 15) * 8;
        const float* p = h + (size_t)row * 128 + cb;
        float4 a0 = ((const float4*)p)[0];
        float4 a1 = ((const float4*)p)[1];
        bf16x8 o;
        o[0] = (short)f2bf(a0.x); o[1] = (short)f2bf(a0.y);
        o[2] = (short)f2bf(a0.z); o[3] = (short)f2bf(a0.w);
        o[4] = (short)f2bf(a1.x); o[5] = (short)f2bf(a1.y);
        o[6] = (short)f2bf(a1.z); o[7] = (short)f2bf(a1.w);
        *(bf16x8*)(A + (size_t)row * A_COLS + cb) = o;
        // histogram: one edge per thread
        atomicAdd(&cnt[dst[t]], 1);
    } else {
        int mat = bid - 3125;                   // 0..3 basis, 4 loop
        const float* src = (mat < 4) ? (basis_w + mat * 16384) : loop_w;
        int koff = (mat < 4) ? (128 + mat * 128) : 0;
        int t = threadIdx.x;
#pragma unroll
        for (int i = 0; i < 16; ++i) {
            int f = t + i * 256;                // [0,4096) float4 index
            int k = f >> 5;                     // source row (k)
            int j4 = (f & 31) * 4;              // source col (j)
            float4 v = ((const float4*)src)[f];
            wt2[(size_t)(j4 + 0) * 640 + koff + k] = f2bf(v.x);
            wt2[(size_t)(j4 + 1) * 640 + koff + k] = f2bf(v.y);
            wt2[(size_t)(j4 + 2) * 640 + koff + k] = f2bf(v.z);
            wt2[(size_t)(j4 + 3) * 640 + koff + k] = f2bf(v.w);
        }
    }
}

// K1a: per-block (256-elem) exclusive scan; writes local scan + block sums.
__global__ __launch_bounds__(256) void scan_local(
        const int* __restrict__ cnt, int* __restrict__ offs,
        int* __restrict__ bsum) {
    __shared__ int wsum[4];
    int t = threadIdx.x, lane = t & 63, w = t >> 6;
    int i = blockIdx.x * 256 + t;
    int x = (i < N_NODES) ? cnt[i] : 0;
    int v = x;
#pragma unroll
    for (int d = 1; d < 64; d <<= 1) {
        int y = __shfl_up(v, d);
        if (lane >= d) v += y;
    }
    if (lane == 63) wsum[w] = v;
    __syncthreads();
    int wpre = 0;
    if (w > 0) wpre += wsum[0];
    if (w > 1) wpre += wsum[1];
    if (w > 2) wpre += wsum[2];
    if (i < N_NODES) offs[i] = wpre + v - x;
    if (t == 255) bsum[blockIdx.x] = wpre + v;
}

// K1b: scan the 196 block sums (single block); writes grand total.
__global__ __launch_bounds__(256) void scan_bsum(
        const int* __restrict__ bsum, int* __restrict__ bpre,
        int* __restrict__ offs) {
    __shared__ int wsum[4];
    int t = threadIdx.x, lane = t & 63, w = t >> 6;
    int x = (t < 196) ? bsum[t] : 0;
    int v = x;
#pragma unroll
    for (int d = 1; d < 64; d <<= 1) {
        int y = __shfl_up(v, d);
        if (lane >= d) v += y;
    }
    if (lane == 63) wsum[w] = v;
    __syncthreads();
    int wpre = 0;
    if (w > 0) wpre += wsum[0];
    if (w > 1) wpre += wsum[1];
    if (w > 2) wpre += wsum[2];
    if (t < 196) bpre[t] = wpre + v - x;
    if (t == 255) offs[N_NODES] = wpre + v;   // = N_EDGES
}

// K1c: add block prefixes; also initialize cursor.
__global__ __launch_bounds__(256) void scan_add(
        int* __restrict__ offs, const int* __restrict__ bpre,
        int* __restrict__ cursor) {
    int i = blockIdx.x * 256 + threadIdx.x;
    if (i < N_NODES) {
        int o = offs[i] + bpre[blockIdx.x];
        offs[i] = o;
        cursor[i] = o;
    }
}

// K2: scatter edges into dst-sorted order; 12 B payload per edge.
__global__ __launch_bounds__(256) void scatter_kernel(
        const int* __restrict__ src, const int* __restrict__ dst,
        const int* __restrict__ etype, const float* __restrict__ norm,
        int* __restrict__ cursor,
        int* __restrict__ sorted_src, uint2* __restrict__ sorted_en) {
    int e = blockIdx.x * 256 + threadIdx.x;
    if (e >= N_EDGES) return;
    int d = dst[e];
    int pos = atomicAdd(&cursor[d], 1);
    sorted_src[pos] = src[e];
    sorted_en[pos] = make_uint2((unsigned)etype[e], __float_as_uint(norm[e]));
}

// K3: per-node aggregation, no atomics. One wave per node; edge metadata is
// wave-uniform -> scalar loads; gather is one 256B row per edge (4B/lane).
// A[v][128 + b*128 + c] = sum_{e->v} cf[b] * A[src_e][c]   (bf16 out)
__global__ __launch_bounds__(256) void aggregate_kernel(
        const int* __restrict__ offs, const int* __restrict__ sorted_src,
        const uint2* __restrict__ sorted_en,
        const float* __restrict__ w_comp,
        unsigned short* __restrict__ A) {
    int v = __builtin_amdgcn_readfirstlane(blockIdx.x * 4 + (threadIdx.x >> 6));
    if (v >= N_NODES) return;
    int lane = threadIdx.x & 63;
    int begin = offs[v];
    int end = offs[v + 1];

    float a0l = 0.f, a0h = 0.f, a1l = 0.f, a1h = 0.f;
    float a2l = 0.f, a2h = 0.f, a3l = 0.f, a3h = 0.f;

    const unsigned int* Au = (const unsigned int*)A;

    int j = begin;
    for (; j + 4 <= end; j += 4) {
        int s0 = sorted_src[j + 0];
        int s1 = sorted_src[j + 1];
        int s2 = sorted_src[j + 2];
        int s3 = sorted_src[j + 3];
        uint2 e0 = sorted_en[j + 0];
        uint2 e1 = sorted_en[j + 1];
        uint2 e2 = sorted_en[j + 2];
        uint2 e3 = sorted_en[j + 3];
        unsigned int u0 = Au[(size_t)s0 * 320 + lane];
        unsigned int u1 = Au[(size_t)s1 * 320 + lane];
        unsigned int u2 = Au[(size_t)s2 * 320 + lane];
        unsigned int u3 = Au[(size_t)s3 * 320 + lane];

        float4 w0 = ((const float4*)w_comp)[e0.x];
        float4 w1 = ((const float4*)w_comp)[e1.x];
        float4 w2 = ((const float4*)w_comp)[e2.x];
        float4 w3 = ((const float4*)w_comp)[e3.x];
        float n0 = __uint_as_float(e0.y), n1 = __uint_as_float(e1.y);
        float n2 = __uint_as_float(e2.y), n3 = __uint_as_float(e3.y);

        float lo, hi;
        lo = __uint_as_float(u0 << 16); hi = __uint_as_float(u0 & 0xffff0000u);
        a0l += (w0.x * n0) * lo; a0h += (w0.x * n0) * hi;
        a1l += (w0.y * n0) * lo; a1h += (w0.y * n0) * hi;
        a2l += (w0.z * n0) * lo; a2h += (w0.z * n0) * hi;
        a3l += (w0.w * n0) * lo; a3h += (w0.w * n0) * hi;
        lo = __uint_as_float(u1 << 16); hi = __uint_as_float(u1 & 0xffff0000u);
        a0l += (w1.x * n1) * lo; a0h += (w1.x * n1) * hi;
        a1l += (w1.y * n1) * lo; a1h += (w1.y * n1) * hi;
        a2l += (w1.z * n1) * lo; a2h += (w1.z * n1) * hi;
        a3l += (w1.w * n1) * lo; a3h += (w1.w * n1) * hi;
        lo = __uint_as_float(u2 << 16); hi = __uint_as_float(u2 & 0xffff0000u);
        a0l += (w2.x * n2) * lo; a0h += (w2.x * n2) * hi;
        a1l += (w2.y * n2) * lo; a1h += (w2.y * n2) * hi;
        a2l += (w2.z * n2) * lo; a2h += (w2.z * n2) * hi;
        a3l += (w2.w * n2) * lo; a3h += (w2.w * n2) * hi;
        lo = __uint_as_float(u3 << 16); hi = __uint_as_float(u3 & 0xffff0000u);
        a0l += (w3.x * n3) * lo; a0h += (w3.x * n3) * hi;
        a1l += (w3.y * n3) * lo; a1h += (w3.y * n3) * hi;
        a2l += (w3.z * n3) * lo; a2h += (w3.z * n3) * hi;
        a3l += (w3.w * n3) * lo; a3h += (w3.w * n3) * hi;
    }
    for (; j < end; ++j) {
        int s = sorted_src[j];
        uint2 en = sorted_en[j];
        float4 wc = ((const float4*)w_comp)[en.x];
        float nm = __uint_as_float(en.y);
        unsigned int u = Au[(size_t)s * 320 + lane];
        float lo = __uint_as_float(u << 16);
        float hi = __uint_as_float(u & 0xffff0000u);
        a0l += (wc.x * nm) * lo; a0h += (wc.x * nm) * hi;
        a1l += (wc.y * nm) * lo; a1h += (wc.y * nm) * hi;
        a2l += (wc.z * nm) * lo; a2h += (wc.z * nm) * hi;
        a3l += (wc.w * nm) * lo; a3h += (wc.w * nm) * hi;
    }

    unsigned int* ps = (unsigned int*)(A + (size_t)v * A_COLS + 128);
    ps[0 * 64 + lane] = (unsigned int)f2bf(a0l) | ((unsigned int)f2bf(a0h) << 16);
    ps[1 * 64 + lane] = (unsigned int)f2bf(a1l) | ((unsigned int)f2bf(a1h) << 16);
    ps[2 * 64 + lane] = (unsigned int)f2bf(a2l) | ((unsigned int)f2bf(a2h) << 16);
    ps[3 * 64 + lane] = (unsigned int)f2bf(a3l) | ((unsigned int)f2bf(a3h) << 16);
}

// K4: out = relu(bias + A @ Wstack)   (M=50048, N=128, K=640 bf16 MFMA GEMM)
// 16 rows per wave, 64 per block, 782 blocks = 3128 waves (~12 waves/CU).
// Register double-buffer prefetch of next k-step's A+B frags.
__global__ __launch_bounds__(256, 3) void gemm_out(
        const unsigned short* __restrict__ A,
        const unsigned short* __restrict__ wt2,
        const float* __restrict__ bias,
        float* __restrict__ out) {
    int wv = threadIdx.x >> 6;
    int lane = threadIdx.x & 63;
    int n16 = lane & 15;
    int quad = lane >> 4;
    int r0 = (blockIdx.x * 4 + wv) * 16;

    const unsigned short* ap = A + (size_t)(r0 + n16) * A_COLS + quad * 8;
    const unsigned short* bp = wt2 + (size_t)n16 * 640 + quad * 8;

    f32x4 acc[8];
#pragma unroll
    for (int ct = 0; ct < 8; ++ct) acc[ct] = (f32x4)0.f;

    bf16x8 a_cur = *(const bf16x8*)ap;
    bf16x8 b_cur[8];
#pragma unroll
    for (int ct = 0; ct < 8; ++ct)
        b_cur[ct] = *(const bf16x8*)(bp + (size_t)ct * 16 * 640);

#pragma unroll
    for (int ks = 0; ks < 20; ++ks) {
        bf16x8 a_nxt = a_cur;
        bf16x8 b_nxt[8];
        if (ks < 19) {
            a_nxt = *(const bf16x8*)(ap + (ks + 1) * 32);
#pragma unroll
            for (int ct = 0; ct < 8; ++ct)
                b_nxt[ct] = *(const bf16x8*)(bp + (size_t)ct * 16 * 640 + (ks + 1) * 32);
        } else {
#pragma unroll
            for (int ct = 0; ct < 8; ++ct) b_nxt[ct] = b_cur[ct];
        }
#pragma unroll
        for (int ct = 0; ct < 8; ++ct)
            acc[ct] = __builtin_amdgcn_mfma_f32_16x16x32_bf16(a_cur, b_cur[ct], acc[ct], 0, 0, 0);
        a_cur = a_nxt;
#pragma unroll
        for (int ct = 0; ct < 8; ++ct) b_cur[ct] = b_nxt[ct];
    }

    // C/D layout: col = lane&15, row = quad*4 + reg
    int rbase = r0 + quad * 4;
#pragma unroll
    for (int ct = 0; ct < 8; ++ct) {
        int col = ct * 16 + n16;
        float bv = bias[col];
#pragma unroll
        for (int rg = 0; rg < 4; ++rg) {
            int r = rbase + rg;
            if (r < N_NODES)
                out[(size_t)r * H_DIM + col] = fmaxf(acc[ct][rg] + bv, 0.f);
        }
    }
}

extern "C" void kernel_launch(void* const* d_in, const int* in_sizes, int n_in,
                              void* d_out, int out_size, void* d_ws, size_t ws_size,
                              hipStream_t stream) {
    const float* h       = (const float*)d_in[0];
    const float* norm    = (const float*)d_in[1];
    const float* basis_w = (const float*)d_in[2];
    const float* w_comp  = (const float*)d_in[3];
    const float* loop_w  = (const float*)d_in[4];
    const float* bias    = (const float*)d_in[5];
    const int*   src     = (const int*)d_in[6];
    const int*   dst     = (const int*)d_in[7];
    const int*   etype   = (const int*)d_in[8];
    float* out = (float*)d_out;

    // ws layout (bytes):
    char* base = (char*)d_ws;
    unsigned short* wt2        = (unsigned short*)(base + 0);          //    163,840
    unsigned short* A          = (unsigned short*)(base + 163840);     // 64,061,440
    int*            cnt        = (int*)(base + 64225280);              //    200,000
    int*            offs       = (int*)(base + 64425280);              //    200,064
    int*            cursor     = (int*)(base + 64625344);              //    200,000
    int*            sorted_src = (int*)(base + 64825344);              //  3,200,000
    uint2*          sorted_en  = (uint2*)(base + 68025344);            //  6,400,000
    int*            bsum       = (int*)(base + 74425344);              //        784
    int*            bpre       = (int*)(base + 74426128);              //        784
    // total ~74.4 MB

    hipMemsetAsync(cnt, 0, N_NODES * sizeof(int), stream);
    prep_kernel<<<3130, 256, 0, stream>>>(h, dst, basis_w, loop_w, A, cnt, wt2);
    scan_local<<<196, 256, 0, stream>>>(cnt, offs, bsum);
    scan_bsum<<<1, 256, 0, stream>>>(bsum, bpre, offs);
    scan_add<<<196, 256, 0, stream>>>(offs, bpre, cursor);
    scatter_kernel<<<3125, 256, 0, stream>>>(src, dst, etype, norm,
                                             cursor, sorted_src, sorted_en);
    aggregate_kernel<<<12500, 256, 0, stream>>>(offs, sorted_src, sorted_en,
                                                w_comp, A);
    gemm_out<<<782, 256, 0, stream>>>(A, wt2, bias, out);
}

// Round 5
// 264.856 us; speedup vs baseline: 1.1662x; 1.1662x over previous
//
#include <hip/hip_runtime.h>
#include <hip/hip_bf16.h>
#include <stdint.h>

#define N_NODES 50000
#define N_EDGES 800000
#define H_DIM 128
#define N_REL 40
#define N_BASES 4
#define A_COLS 640           // [hbf(128) | S(512)] unified per-node row
#define N_ROWS_PAD 50048     // 391 blocks * 128 rows

typedef __attribute__((ext_vector_type(8))) short bf16x8;
typedef __attribute__((ext_vector_type(4))) float f32x4;

// round-to-nearest-even f32 -> bf16 bits
__device__ __forceinline__ unsigned short f2bf(float f) {
    unsigned int u = __float_as_uint(f);
    unsigned int r = u + 0x7fffu + ((u >> 16) & 1u);
    return (unsigned short)(r >> 16);
}

// ---------------------------------------------------------------------------
// K0 "prep": blocks 0..3124  -> cast h into A[:,0:128] (bf16) + dst histogram
//            blocks 3125..3129 -> repack loop_w/basis_w into frag-major wt3
// wt3 layout: frag (ks, cg) occupies 512 bf16 at ((ks*8+cg)*64 + lane)*8 + j,
// holding Wstack[ks*32 + (lane>>4)*8 + j][cg*16 + (lane&15)], where
// Wstack = [loop_w ; basis_w[0..3]] (640 x 128). A wave's frag load is a
// contiguous 1 KB block -> fully coalesced.
__global__ __launch_bounds__(256) void prep_kernel(
        const float* __restrict__ h, const int* __restrict__ dst,
        const float* __restrict__ basis_w, const float* __restrict__ loop_w,
        unsigned short* __restrict__ A, int* __restrict__ cnt,
        unsigned short* __restrict__ wt3) {
    int bid = blockIdx.x;
    if (bid < 3125) {
        int t = bid * 256 + threadIdx.x;        // [0, 800000)
        // cast: 8 elems of h per thread
        int row = t >> 4;
        int cb = (t & 15) * 8;
        const float* p = h + (size_t)row * 128 + cb;
        float4 a0 = ((const float4*)p)[0];
        float4 a1 = ((const float4*)p)[1];
        bf16x8 o;
        o[0] = (short)f2bf(a0.x); o[1] = (short)f2bf(a0.y);
        o[2] = (short)f2bf(a0.z); o[3] = (short)f2bf(a0.w);
        o[4] = (short)f2bf(a1.x); o[5] = (short)f2bf(a1.y);
        o[6] = (short)f2bf(a1.z); o[7] = (short)f2bf(a1.w);
        *(bf16x8*)(A + (size_t)row * A_COLS + cb) = o;
        // histogram: one edge per thread
        atomicAdd(&cnt[dst[t]], 1);
    } else {
        int mat = bid - 3125;                   // 0..3 basis, 4 loop
        const float* src = (mat < 4) ? (basis_w + mat * 16384) : loop_w;
        int koff = (mat < 4) ? (128 + mat * 128) : 0;
        int t = threadIdx.x;
#pragma unroll
        for (int i = 0; i < 16; ++i) {
            int f = t + i * 256;                // [0,4096) float4 index
            int k = f >> 5;                     // source row (k within mat)
            int j4 = (f & 31) * 4;              // source col (j)
            float4 v = ((const float4*)src)[f];
            int kg = koff + k;
            int ks = kg >> 5;
            int quad = (kg >> 3) & 3;
            int jj = kg & 7;
            float vv[4] = {v.x, v.y, v.z, v.w};
#pragma unroll
            for (int d = 0; d < 4; ++d) {
                int j = j4 + d;
                int cg = j >> 4;
                int n16 = j & 15;
                wt3[(size_t)((ks * 8 + cg) * 64 + quad * 16 + n16) * 8 + jj] =
                    f2bf(vv[d]);
            }
        }
    }
}

// K1a: per-block (256-elem) exclusive scan; writes local scan + block sums.
__global__ __launch_bounds__(256) void scan_local(
        const int* __restrict__ cnt, int* __restrict__ offs,
        int* __restrict__ bsum) {
    __shared__ int wsum[4];
    int t = threadIdx.x, lane = t & 63, w = t >> 6;
    int i = blockIdx.x * 256 + t;
    int x = (i < N_NODES) ? cnt[i] : 0;
    int v = x;
#pragma unroll
    for (int d = 1; d < 64; d <<= 1) {
        int y = __shfl_up(v, d);
        if (lane >= d) v += y;
    }
    if (lane == 63) wsum[w] = v;
    __syncthreads();
    int wpre = 0;
    if (w > 0) wpre += wsum[0];
    if (w > 1) wpre += wsum[1];
    if (w > 2) wpre += wsum[2];
    if (i < N_NODES) offs[i] = wpre + v - x;
    if (t == 255) bsum[blockIdx.x] = wpre + v;
}

// K1b: scan the 196 block sums (single block); writes grand total.
__global__ __launch_bounds__(256) void scan_bsum(
        const int* __restrict__ bsum, int* __restrict__ bpre,
        int* __restrict__ offs) {
    __shared__ int wsum[4];
    int t = threadIdx.x, lane = t & 63, w = t >> 6;
    int x = (t < 196) ? bsum[t] : 0;
    int v = x;
#pragma unroll
    for (int d = 1; d < 64; d <<= 1) {
        int y = __shfl_up(v, d);
        if (lane >= d) v += y;
    }
    if (lane == 63) wsum[w] = v;
    __syncthreads();
    int wpre = 0;
    if (w > 0) wpre += wsum[0];
    if (w > 1) wpre += wsum[1];
    if (w > 2) wpre += wsum[2];
    if (t < 196) bpre[t] = wpre + v - x;
    if (t == 255) offs[N_NODES] = wpre + v;   // = N_EDGES
}

// K1c: add block prefixes; also initialize cursor.
__global__ __launch_bounds__(256) void scan_add(
        int* __restrict__ offs, const int* __restrict__ bpre,
        int* __restrict__ cursor) {
    int i = blockIdx.x * 256 + threadIdx.x;
    if (i < N_NODES) {
        int o = offs[i] + bpre[blockIdx.x];
        offs[i] = o;
        cursor[i] = o;
    }
}

// K2: scatter edges into dst-sorted order; 12 B payload per edge.
__global__ __launch_bounds__(256) void scatter_kernel(
        const int* __restrict__ src, const int* __restrict__ dst,
        const int* __restrict__ etype, const float* __restrict__ norm,
        int* __restrict__ cursor,
        int* __restrict__ sorted_src, uint2* __restrict__ sorted_en) {
    int e = blockIdx.x * 256 + threadIdx.x;
    if (e >= N_EDGES) return;
    int d = dst[e];
    int pos = atomicAdd(&cursor[d], 1);
    sorted_src[pos] = src[e];
    sorted_en[pos] = make_uint2((unsigned)etype[e], __float_as_uint(norm[e]));
}

// K3: per-node aggregation, no atomics. One wave per node; edge metadata is
// wave-uniform -> scalar loads; gather is one 256B row per edge (4B/lane).
// A[v][128 + b*128 + c] = sum_{e->v} cf[b] * A[src_e][c]   (bf16 out)
__global__ __launch_bounds__(256) void aggregate_kernel(
        const int* __restrict__ offs, const int* __restrict__ sorted_src,
        const uint2* __restrict__ sorted_en,
        const float* __restrict__ w_comp,
        unsigned short* __restrict__ A) {
    int v = __builtin_amdgcn_readfirstlane(blockIdx.x * 4 + (threadIdx.x >> 6));
    if (v >= N_NODES) return;
    int lane = threadIdx.x & 63;
    int begin = offs[v];
    int end = offs[v + 1];

    float a0l = 0.f, a0h = 0.f, a1l = 0.f, a1h = 0.f;
    float a2l = 0.f, a2h = 0.f, a3l = 0.f, a3h = 0.f;

    const unsigned int* Au = (const unsigned int*)A;

    int j = begin;
    for (; j + 4 <= end; j += 4) {
        int s0 = sorted_src[j + 0];
        int s1 = sorted_src[j + 1];
        int s2 = sorted_src[j + 2];
        int s3 = sorted_src[j + 3];
        uint2 e0 = sorted_en[j + 0];
        uint2 e1 = sorted_en[j + 1];
        uint2 e2 = sorted_en[j + 2];
        uint2 e3 = sorted_en[j + 3];
        unsigned int u0 = Au[(size_t)s0 * 320 + lane];
        unsigned int u1 = Au[(size_t)s1 * 320 + lane];
        unsigned int u2 = Au[(size_t)s2 * 320 + lane];
        unsigned int u3 = Au[(size_t)s3 * 320 + lane];

        float4 w0 = ((const float4*)w_comp)[e0.x];
        float4 w1 = ((const float4*)w_comp)[e1.x];
        float4 w2 = ((const float4*)w_comp)[e2.x];
        float4 w3 = ((const float4*)w_comp)[e3.x];
        float n0 = __uint_as_float(e0.y), n1 = __uint_as_float(e1.y);
        float n2 = __uint_as_float(e2.y), n3 = __uint_as_float(e3.y);

        float lo, hi;
        lo = __uint_as_float(u0 << 16); hi = __uint_as_float(u0 & 0xffff0000u);
        a0l += (w0.x * n0) * lo; a0h += (w0.x * n0) * hi;
        a1l += (w0.y * n0) * lo; a1h += (w0.y * n0) * hi;
        a2l += (w0.z * n0) * lo; a2h += (w0.z * n0) * hi;
        a3l += (w0.w * n0) * lo; a3h += (w0.w * n0) * hi;
        lo = __uint_as_float(u1 << 16); hi = __uint_as_float(u1 & 0xffff0000u);
        a0l += (w1.x * n1) * lo; a0h += (w1.x * n1) * hi;
        a1l += (w1.y * n1) * lo; a1h += (w1.y * n1) * hi;
        a2l += (w1.z * n1) * lo; a2h += (w1.z * n1) * hi;
        a3l += (w1.w * n1) * lo; a3h += (w1.w * n1) * hi;
        lo = __uint_as_float(u2 << 16); hi = __uint_as_float(u2 & 0xffff0000u);
        a0l += (w2.x * n2) * lo; a0h += (w2.x * n2) * hi;
        a1l += (w2.y * n2) * lo; a1h += (w2.y * n2) * hi;
        a2l += (w2.z * n2) * lo; a2h += (w2.z * n2) * hi;
        a3l += (w2.w * n2) * lo; a3h += (w2.w * n2) * hi;
        lo = __uint_as_float(u3 << 16); hi = __uint_as_float(u3 & 0xffff0000u);
        a0l += (w3.x * n3) * lo; a0h += (w3.x * n3) * hi;
        a1l += (w3.y * n3) * lo; a1h += (w3.y * n3) * hi;
        a2l += (w3.z * n3) * lo; a2h += (w3.z * n3) * hi;
        a3l += (w3.w * n3) * lo; a3h += (w3.w * n3) * hi;
    }
    for (; j < end; ++j) {
        int s = sorted_src[j];
        uint2 en = sorted_en[j];
        float4 wc = ((const float4*)w_comp)[en.x];
        float nm = __uint_as_float(en.y);
        unsigned int u = Au[(size_t)s * 320 + lane];
        float lo = __uint_as_float(u << 16);
        float hi = __uint_as_float(u & 0xffff0000u);
        a0l += (wc.x * nm) * lo; a0h += (wc.x * nm) * hi;
        a1l += (wc.y * nm) * lo; a1h += (wc.y * nm) * hi;
        a2l += (wc.z * nm) * lo; a2h += (wc.z * nm) * hi;
        a3l += (wc.w * nm) * lo; a3h += (wc.w * nm) * hi;
    }

    unsigned int* ps = (unsigned int*)(A + (size_t)v * A_COLS + 128);
    ps[0 * 64 + lane] = (unsigned int)f2bf(a0l) | ((unsigned int)f2bf(a0h) << 16);
    ps[1 * 64 + lane] = (unsigned int)f2bf(a1l) | ((unsigned int)f2bf(a1h) << 16);
    ps[2 * 64 + lane] = (unsigned int)f2bf(a2l) | ((unsigned int)f2bf(a2h) << 16);
    ps[3 * 64 + lane] = (unsigned int)f2bf(a3l) | ((unsigned int)f2bf(a3h) << 16);
}

// K4: out = relu(bias + A @ Wstack)   (M=50048, N=128, K=640 bf16 MFMA GEMM)
// Wave = 32 rows x 64 cols; block = 128 rows x 64 cols; grid (391, 2).
// 3128 waves (~12/CU). B frags are frag-major (contiguous 1 KB per load).
// Register double-buffer prefetch of next k-step's A+B frags.
__global__ __launch_bounds__(256, 4) void gemm_out(
        const unsigned short* __restrict__ A,
        const unsigned short* __restrict__ wt3,
        const float* __restrict__ bias,
        float* __restrict__ out) {
    int wv = threadIdx.x >> 6;
    int lane = threadIdx.x & 63;
    int n16 = lane & 15;
    int quad = lane >> 4;
    int r0 = (blockIdx.x * 4 + wv) * 32;
    int ch = blockIdx.y;            // column half (0/1)

    const unsigned short* ap0 = A + (size_t)(r0 + n16) * A_COLS + quad * 8;
    const unsigned short* ap1 = ap0 + 16 * A_COLS;
    // frag (ks, cg=ch*4+ct) base: wt3 + (ks*8+cg)*512 + lane*8
    const unsigned short* bp = wt3 + (size_t)(ch * 4) * 512 + (size_t)lane * 8;

    f32x4 acc[2][4];
#pragma unroll
    for (int rt = 0; rt < 2; ++rt)
#pragma unroll
        for (int ct = 0; ct < 4; ++ct)
            acc[rt][ct] = (f32x4)0.f;

    bf16x8 a_cur[2], b_cur[4];
    a_cur[0] = *(const bf16x8*)ap0;
    a_cur[1] = *(const bf16x8*)ap1;
#pragma unroll
    for (int ct = 0; ct < 4; ++ct)
        b_cur[ct] = *(const bf16x8*)(bp + ct * 512);

#pragma unroll
    for (int ks = 0; ks < 20; ++ks) {
        bf16x8 a_nxt[2], b_nxt[4];
        if (ks < 19) {
            a_nxt[0] = *(const bf16x8*)(ap0 + (ks + 1) * 32);
            a_nxt[1] = *(const bf16x8*)(ap1 + (ks + 1) * 32);
#pragma unroll
            for (int ct = 0; ct < 4; ++ct)
                b_nxt[ct] = *(const bf16x8*)(bp + (ks + 1) * 4096 + ct * 512);
        } else {
            a_nxt[0] = a_cur[0];
            a_nxt[1] = a_cur[1];
#pragma unroll
            for (int ct = 0; ct < 4; ++ct) b_nxt[ct] = b_cur[ct];
        }
#pragma unroll
        for (int ct = 0; ct < 4; ++ct) {
            acc[0][ct] = __builtin_amdgcn_mfma_f32_16x16x32_bf16(a_cur[0], b_cur[ct], acc[0][ct], 0, 0, 0);
            acc[1][ct] = __builtin_amdgcn_mfma_f32_16x16x32_bf16(a_cur[1], b_cur[ct], acc[1][ct], 0, 0, 0);
        }
        a_cur[0] = a_nxt[0];
        a_cur[1] = a_nxt[1];
#pragma unroll
        for (int ct = 0; ct < 4; ++ct) b_cur[ct] = b_nxt[ct];
    }

    // C/D layout: col = lane&15, row = quad*4 + reg
#pragma unroll
    for (int rt = 0; rt < 2; ++rt) {
        int rbase = r0 + rt * 16 + quad * 4;
#pragma unroll
        for (int ct = 0; ct < 4; ++ct) {
            int col = ch * 64 + ct * 16 + n16;
            float bv = bias[col];
#pragma unroll
            for (int rg = 0; rg < 4; ++rg) {
                int r = rbase + rg;
                if (r < N_NODES)
                    out[(size_t)r * H_DIM + col] = fmaxf(acc[rt][ct][rg] + bv, 0.f);
            }
        }
    }
}

extern "C" void kernel_launch(void* const* d_in, const int* in_sizes, int n_in,
                              void* d_out, int out_size, void* d_ws, size_t ws_size,
                              hipStream_t stream) {
    const float* h       = (const float*)d_in[0];
    const float* norm    = (const float*)d_in[1];
    const float* basis_w = (const float*)d_in[2];
    const float* w_comp  = (const float*)d_in[3];
    const float* loop_w  = (const float*)d_in[4];
    const float* bias    = (const float*)d_in[5];
    const int*   src     = (const int*)d_in[6];
    const int*   dst     = (const int*)d_in[7];
    const int*   etype   = (const int*)d_in[8];
    float* out = (float*)d_out;

    // ws layout (bytes):
    char* base = (char*)d_ws;
    unsigned short* wt3        = (unsigned short*)(base + 0);          //    163,840
    unsigned short* A          = (unsigned short*)(base + 163840);     // 64,061,440
    int*            cnt        = (int*)(base + 64225280);              //    200,000
    int*            offs       = (int*)(base + 64425280);              //    200,064
    int*            cursor     = (int*)(base + 64625344);              //    200,000
    int*            sorted_src = (int*)(base + 64825344);              //  3,200,000
    uint2*          sorted_en  = (uint2*)(base + 68025344);            //  6,400,000
    int*            bsum       = (int*)(base + 74425344);              //        784
    int*            bpre       = (int*)(base + 74426128);              //        784
    // total ~74.4 MB

    hipMemsetAsync(cnt, 0, N_NODES * sizeof(int), stream);
    prep_kernel<<<3130, 256, 0, stream>>>(h, dst, basis_w, loop_w, A, cnt, wt3);
    scan_local<<<196, 256, 0, stream>>>(cnt, offs, bsum);
    scan_bsum<<<1, 256, 0, stream>>>(bsum, bpre, offs);
    scan_add<<<196, 256, 0, stream>>>(offs, bpre, cursor);
    scatter_kernel<<<3125, 256, 0, stream>>>(src, dst, etype, norm,
                                             cursor, sorted_src, sorted_en);
    aggregate_kernel<<<12500, 256, 0, stream>>>(offs, sorted_src, sorted_en,
                                                w_comp, A);
    gemm_out<<<dim3(391, 2), 256, 0, stream>>>(A, wt3, bias, out);
}

// Round 6
// 257.544 us; speedup vs baseline: 1.1993x; 1.0284x over previous
//
#include <hip/hip_runtime.h>
#include <hip/hip_bf16.h>
#include <stdint.h>

#define N_NODES 50000
#define N_EDGES 800000
#define H_DIM 128
#define N_REL 40
#define N_BASES 4
#define A_COLS 640           // [hbf(128) | S(512)] unified per-node row
#define N_ROWS_PAD 50048     // 391 blocks * 128 rows

typedef __attribute__((ext_vector_type(8))) short bf16x8;
typedef __attribute__((ext_vector_type(4))) float f32x4;

// round-to-nearest-even f32 -> bf16 bits
__device__ __forceinline__ unsigned short f2bf(float f) {
    unsigned int u = __float_as_uint(f);
    unsigned int r = u + 0x7fffu + ((u >> 16) & 1u);
    return (unsigned short)(r >> 16);
}

// ---------------------------------------------------------------------------
// K0 "prep": blocks 0..3124  -> cast h into A[:,0:128] (bf16) + dst histogram
//            blocks 3125..3129 -> repack loop_w/basis_w into frag-major wt3
// wt3 layout: frag (ks, cg) occupies 512 bf16 at ((ks*8+cg)*64 + lane)*8 + j,
// holding Wstack[ks*32 + (lane>>4)*8 + j][cg*16 + (lane&15)], where
// Wstack = [loop_w ; basis_w[0..3]] (640 x 128). A wave's frag load is a
// contiguous 1 KB block -> fully coalesced.
__global__ __launch_bounds__(256) void prep_kernel(
        const float* __restrict__ h, const int* __restrict__ dst,
        const float* __restrict__ basis_w, const float* __restrict__ loop_w,
        unsigned short* __restrict__ A, int* __restrict__ cnt,
        unsigned short* __restrict__ wt3) {
    int bid = blockIdx.x;
    if (bid < 3125) {
        int t = bid * 256 + threadIdx.x;        // [0, 800000)
        // cast: 8 elems of h per thread
        int row = t >> 4;
        int cb = (t & 15) * 8;
        const float* p = h + (size_t)row * 128 + cb;
        float4 a0 = ((const float4*)p)[0];
        float4 a1 = ((const float4*)p)[1];
        bf16x8 o;
        o[0] = (short)f2bf(a0.x); o[1] = (short)f2bf(a0.y);
        o[2] = (short)f2bf(a0.z); o[3] = (short)f2bf(a0.w);
        o[4] = (short)f2bf(a1.x); o[5] = (short)f2bf(a1.y);
        o[6] = (short)f2bf(a1.z); o[7] = (short)f2bf(a1.w);
        *(bf16x8*)(A + (size_t)row * A_COLS + cb) = o;
        // histogram: one edge per thread
        atomicAdd(&cnt[dst[t]], 1);
    } else {
        int mat = bid - 3125;                   // 0..3 basis, 4 loop
        const float* src = (mat < 4) ? (basis_w + mat * 16384) : loop_w;
        int koff = (mat < 4) ? (128 + mat * 128) : 0;
        int t = threadIdx.x;
#pragma unroll
        for (int i = 0; i < 16; ++i) {
            int f = t + i * 256;                // [0,4096) float4 index
            int k = f >> 5;                     // source row (k within mat)
            int j4 = (f & 31) * 4;              // source col (j)
            float4 v = ((const float4*)src)[f];
            int kg = koff + k;
            int ks = kg >> 5;
            int quad = (kg >> 3) & 3;
            int jj = kg & 7;
            float vv[4] = {v.x, v.y, v.z, v.w};
#pragma unroll
            for (int d = 0; d < 4; ++d) {
                int j = j4 + d;
                int cg = j >> 4;
                int n16 = j & 15;
                wt3[(size_t)((ks * 8 + cg) * 64 + quad * 16 + n16) * 8 + jj] =
                    f2bf(vv[d]);
            }
        }
    }
}

// K1a: per-block (256-elem) exclusive scan; writes local scan + block sums.
__global__ __launch_bounds__(256) void scan_local(
        const int* __restrict__ cnt, int* __restrict__ offs,
        int* __restrict__ bsum) {
    __shared__ int wsum[4];
    int t = threadIdx.x, lane = t & 63, w = t >> 6;
    int i = blockIdx.x * 256 + t;
    int x = (i < N_NODES) ? cnt[i] : 0;
    int v = x;
#pragma unroll
    for (int d = 1; d < 64; d <<= 1) {
        int y = __shfl_up(v, d);
        if (lane >= d) v += y;
    }
    if (lane == 63) wsum[w] = v;
    __syncthreads();
    int wpre = 0;
    if (w > 0) wpre += wsum[0];
    if (w > 1) wpre += wsum[1];
    if (w > 2) wpre += wsum[2];
    if (i < N_NODES) offs[i] = wpre + v - x;
    if (t == 255) bsum[blockIdx.x] = wpre + v;
}

// K1b: scan the 196 block sums (single block); writes grand total.
__global__ __launch_bounds__(256) void scan_bsum(
        const int* __restrict__ bsum, int* __restrict__ bpre,
        int* __restrict__ offs) {
    __shared__ int wsum[4];
    int t = threadIdx.x, lane = t & 63, w = t >> 6;
    int x = (t < 196) ? bsum[t] : 0;
    int v = x;
#pragma unroll
    for (int d = 1; d < 64; d <<= 1) {
        int y = __shfl_up(v, d);
        if (lane >= d) v += y;
    }
    if (lane == 63) wsum[w] = v;
    __syncthreads();
    int wpre = 0;
    if (w > 0) wpre += wsum[0];
    if (w > 1) wpre += wsum[1];
    if (w > 2) wpre += wsum[2];
    if (t < 196) bpre[t] = wpre + v - x;
    if (t == 255) offs[N_NODES] = wpre + v;   // = N_EDGES
}

// K1c: add block prefixes; also initialize cursor.
__global__ __launch_bounds__(256) void scan_add(
        int* __restrict__ offs, const int* __restrict__ bpre,
        int* __restrict__ cursor) {
    int i = blockIdx.x * 256 + threadIdx.x;
    if (i < N_NODES) {
        int o = offs[i] + bpre[blockIdx.x];
        offs[i] = o;
        cursor[i] = o;
    }
}

// K2: scatter edges into dst-sorted order; ONE 8 B write per edge:
// pkd.x = src | (etype << 20), pkd.y = f32 norm bits.
__global__ __launch_bounds__(256) void scatter_kernel(
        const int* __restrict__ src, const int* __restrict__ dst,
        const int* __restrict__ etype, const float* __restrict__ norm,
        int* __restrict__ cursor, uint2* __restrict__ sorted_pe) {
    int e = blockIdx.x * 256 + threadIdx.x;
    if (e >= N_EDGES) return;
    int d = dst[e];
    int pos = atomicAdd(&cursor[d], 1);
    sorted_pe[pos] = make_uint2((unsigned)src[e] | ((unsigned)etype[e] << 20),
                                __float_as_uint(norm[e]));
}

// K3: per-node aggregation, no atomics. One wave per node; edge metadata is
// wave-uniform -> scalar loads; gather is one 256B row per edge (4B/lane).
// A[v][128 + b*128 + c] = sum_{e->v} cf[b] * A[src_e][c]   (bf16 out)
__global__ __launch_bounds__(256) void aggregate_kernel(
        const int* __restrict__ offs, const uint2* __restrict__ sorted_pe,
        const float* __restrict__ w_comp,
        unsigned short* __restrict__ A) {
    int v = __builtin_amdgcn_readfirstlane(blockIdx.x * 4 + (threadIdx.x >> 6));
    if (v >= N_NODES) return;
    int lane = threadIdx.x & 63;
    int begin = offs[v];
    int end = offs[v + 1];

    float a0l = 0.f, a0h = 0.f, a1l = 0.f, a1h = 0.f;
    float a2l = 0.f, a2h = 0.f, a3l = 0.f, a3h = 0.f;

    const unsigned int* Au = (const unsigned int*)A;

    int j = begin;
    for (; j + 4 <= end; j += 4) {
        uint2 p0 = sorted_pe[j + 0];
        uint2 p1 = sorted_pe[j + 1];
        uint2 p2 = sorted_pe[j + 2];
        uint2 p3 = sorted_pe[j + 3];
        int s0 = p0.x & 0xFFFFF;
        int s1 = p1.x & 0xFFFFF;
        int s2 = p2.x & 0xFFFFF;
        int s3 = p3.x & 0xFFFFF;
        unsigned int u0 = Au[(size_t)s0 * 320 + lane];
        unsigned int u1 = Au[(size_t)s1 * 320 + lane];
        unsigned int u2 = Au[(size_t)s2 * 320 + lane];
        unsigned int u3 = Au[(size_t)s3 * 320 + lane];

        float4 w0 = ((const float4*)w_comp)[p0.x >> 20];
        float4 w1 = ((const float4*)w_comp)[p1.x >> 20];
        float4 w2 = ((const float4*)w_comp)[p2.x >> 20];
        float4 w3 = ((const float4*)w_comp)[p3.x >> 20];
        float n0 = __uint_as_float(p0.y), n1 = __uint_as_float(p1.y);
        float n2 = __uint_as_float(p2.y), n3 = __uint_as_float(p3.y);

        float lo, hi;
        lo = __uint_as_float(u0 << 16); hi = __uint_as_float(u0 & 0xffff0000u);
        a0l += (w0.x * n0) * lo; a0h += (w0.x * n0) * hi;
        a1l += (w0.y * n0) * lo; a1h += (w0.y * n0) * hi;
        a2l += (w0.z * n0) * lo; a2h += (w0.z * n0) * hi;
        a3l += (w0.w * n0) * lo; a3h += (w0.w * n0) * hi;
        lo = __uint_as_float(u1 << 16); hi = __uint_as_float(u1 & 0xffff0000u);
        a0l += (w1.x * n1) * lo; a0h += (w1.x * n1) * hi;
        a1l += (w1.y * n1) * lo; a1h += (w1.y * n1) * hi;
        a2l += (w1.z * n1) * lo; a2h += (w1.z * n1) * hi;
        a3l += (w1.w * n1) * lo; a3h += (w1.w * n1) * hi;
        lo = __uint_as_float(u2 << 16); hi = __uint_as_float(u2 & 0xffff0000u);
        a0l += (w2.x * n2) * lo; a0h += (w2.x * n2) * hi;
        a1l += (w2.y * n2) * lo; a1h += (w2.y * n2) * hi;
        a2l += (w2.z * n2) * lo; a2h += (w2.z * n2) * hi;
        a3l += (w2.w * n2) * lo; a3h += (w2.w * n2) * hi;
        lo = __uint_as_float(u3 << 16); hi = __uint_as_float(u3 & 0xffff0000u);
        a0l += (w3.x * n3) * lo; a0h += (w3.x * n3) * hi;
        a1l += (w3.y * n3) * lo; a1h += (w3.y * n3) * hi;
        a2l += (w3.z * n3) * lo; a2h += (w3.z * n3) * hi;
        a3l += (w3.w * n3) * lo; a3h += (w3.w * n3) * hi;
    }
    for (; j < end; ++j) {
        uint2 p = sorted_pe[j];
        int s = p.x & 0xFFFFF;
        float4 wc = ((const float4*)w_comp)[p.x >> 20];
        float nm = __uint_as_float(p.y);
        unsigned int u = Au[(size_t)s * 320 + lane];
        float lo = __uint_as_float(u << 16);
        float hi = __uint_as_float(u & 0xffff0000u);
        a0l += (wc.x * nm) * lo; a0h += (wc.x * nm) * hi;
        a1l += (wc.y * nm) * lo; a1h += (wc.y * nm) * hi;
        a2l += (wc.z * nm) * lo; a2h += (wc.z * nm) * hi;
        a3l += (wc.w * nm) * lo; a3h += (wc.w * nm) * hi;
    }

    unsigned int* ps = (unsigned int*)(A + (size_t)v * A_COLS + 128);
    ps[0 * 64 + lane] = (unsigned int)f2bf(a0l) | ((unsigned int)f2bf(a0h) << 16);
    ps[1 * 64 + lane] = (unsigned int)f2bf(a1l) | ((unsigned int)f2bf(a1h) << 16);
    ps[2 * 64 + lane] = (unsigned int)f2bf(a2l) | ((unsigned int)f2bf(a2h) << 16);
    ps[3 * 64 + lane] = (unsigned int)f2bf(a3l) | ((unsigned int)f2bf(a3h) << 16);
}

// K4: out = relu(bias + A @ Wstack)   (M=50048, N=128, K=640 bf16 MFMA GEMM)
// Wave = 32 rows x 64 cols; block = 128 rows x 64 cols; grid (391, 2).
// 3128 waves (~12/CU). B frags are frag-major (contiguous 1 KB per load).
// Register double-buffer prefetch of next k-step's A+B frags.
__global__ __launch_bounds__(256, 4) void gemm_out(
        const unsigned short* __restrict__ A,
        const unsigned short* __restrict__ wt3,
        const float* __restrict__ bias,
        float* __restrict__ out) {
    int wv = threadIdx.x >> 6;
    int lane = threadIdx.x & 63;
    int n16 = lane & 15;
    int quad = lane >> 4;
    int r0 = (blockIdx.x * 4 + wv) * 32;
    int ch = blockIdx.y;            // column half (0/1)

    const unsigned short* ap0 = A + (size_t)(r0 + n16) * A_COLS + quad * 8;
    const unsigned short* ap1 = ap0 + 16 * A_COLS;
    // frag (ks, cg=ch*4+ct) base: wt3 + (ks*8+cg)*512 + lane*8
    const unsigned short* bp = wt3 + (size_t)(ch * 4) * 512 + (size_t)lane * 8;

    f32x4 acc[2][4];
#pragma unroll
    for (int rt = 0; rt < 2; ++rt)
#pragma unroll
        for (int ct = 0; ct < 4; ++ct)
            acc[rt][ct] = (f32x4)0.f;

    bf16x8 a_cur[2], b_cur[4];
    a_cur[0] = *(const bf16x8*)ap0;
    a_cur[1] = *(const bf16x8*)ap1;
#pragma unroll
    for (int ct = 0; ct < 4; ++ct)
        b_cur[ct] = *(const bf16x8*)(bp + ct * 512);

#pragma unroll
    for (int ks = 0; ks < 20; ++ks) {
        bf16x8 a_nxt[2], b_nxt[4];
        if (ks < 19) {
            a_nxt[0] = *(const bf16x8*)(ap0 + (ks + 1) * 32);
            a_nxt[1] = *(const bf16x8*)(ap1 + (ks + 1) * 32);
#pragma unroll
            for (int ct = 0; ct < 4; ++ct)
                b_nxt[ct] = *(const bf16x8*)(bp + (ks + 1) * 4096 + ct * 512);
        } else {
            a_nxt[0] = a_cur[0];
            a_nxt[1] = a_cur[1];
#pragma unroll
            for (int ct = 0; ct < 4; ++ct) b_nxt[ct] = b_cur[ct];
        }
#pragma unroll
        for (int ct = 0; ct < 4; ++ct) {
            acc[0][ct] = __builtin_amdgcn_mfma_f32_16x16x32_bf16(a_cur[0], b_cur[ct], acc[0][ct], 0, 0, 0);
            acc[1][ct] = __builtin_amdgcn_mfma_f32_16x16x32_bf16(a_cur[1], b_cur[ct], acc[1][ct], 0, 0, 0);
        }
        a_cur[0] = a_nxt[0];
        a_cur[1] = a_nxt[1];
#pragma unroll
        for (int ct = 0; ct < 4; ++ct) b_cur[ct] = b_nxt[ct];
    }

    // C/D layout: col = lane&15, row = quad*4 + reg
#pragma unroll
    for (int rt = 0; rt < 2; ++rt) {
        int rbase = r0 + rt * 16 + quad * 4;
#pragma unroll
        for (int ct = 0; ct < 4; ++ct) {
            int col = ch * 64 + ct * 16 + n16;
            float bv = bias[col];
#pragma unroll
            for (int rg = 0; rg < 4; ++rg) {
                int r = rbase + rg;
                if (r < N_NODES)
                    out[(size_t)r * H_DIM + col] = fmaxf(acc[rt][ct][rg] + bv, 0.f);
            }
        }
    }
}

extern "C" void kernel_launch(void* const* d_in, const int* in_sizes, int n_in,
                              void* d_out, int out_size, void* d_ws, size_t ws_size,
                              hipStream_t stream) {
    const float* h       = (const float*)d_in[0];
    const float* norm    = (const float*)d_in[1];
    const float* basis_w = (const float*)d_in[2];
    const float* w_comp  = (const float*)d_in[3];
    const float* loop_w  = (const float*)d_in[4];
    const float* bias    = (const float*)d_in[5];
    const int*   src     = (const int*)d_in[6];
    const int*   dst     = (const int*)d_in[7];
    const int*   etype   = (const int*)d_in[8];
    float* out = (float*)d_out;

    // ws layout (bytes):
    char* base = (char*)d_ws;
    unsigned short* wt3        = (unsigned short*)(base + 0);          //    163,840
    unsigned short* A          = (unsigned short*)(base + 163840);     // 64,061,440
    int*            cnt        = (int*)(base + 64225280);              //    200,000
    int*            offs       = (int*)(base + 64425280);              //    200,064
    int*            cursor     = (int*)(base + 64625344);              //    200,000
    uint2*          sorted_pe  = (uint2*)(base + 64825344);            //  6,400,000
    int*            bsum       = (int*)(base + 71225344);              //        784
    int*            bpre       = (int*)(base + 71226128);              //        784
    // total ~71.2 MB

    hipMemsetAsync(cnt, 0, N_NODES * sizeof(int), stream);
    prep_kernel<<<3130, 256, 0, stream>>>(h, dst, basis_w, loop_w, A, cnt, wt3);
    scan_local<<<196, 256, 0, stream>>>(cnt, offs, bsum);
    scan_bsum<<<1, 256, 0, stream>>>(bsum, bpre, offs);
    scan_add<<<196, 256, 0, stream>>>(offs, bpre, cursor);
    scatter_kernel<<<3125, 256, 0, stream>>>(src, dst, etype, norm,
                                             cursor, sorted_pe);
    aggregate_kernel<<<12500, 256, 0, stream>>>(offs, sorted_pe, w_comp, A);
    gemm_out<<<dim3(391, 2), 256, 0, stream>>>(A, wt3, bias, out);
}